// Round 11
// baseline (196.406 us; speedup 1.0000x reference)
//
#include <hip/hip_runtime.h>

typedef __bf16 bf16x8 __attribute__((ext_vector_type(8)));
typedef __bf16 bf16x4 __attribute__((ext_vector_type(4)));
typedef __bf16 bf16x2 __attribute__((ext_vector_type(2)));
typedef float  floatx4 __attribute__((ext_vector_type(4)));
typedef unsigned int uint32;
typedef uint32 uintx4 __attribute__((ext_vector_type(4)));

#define MFMA16(a,b,c) __builtin_amdgcn_mfma_f32_16x16x32_bf16(a,b,c,0,0,0)

constexpr int DIM  = 512;
constexpr int SEQ  = 4096;
constexpr int HD   = 64;
// 0.125 (HEAD_DIM^-0.5) * log2(e), folded into Q so softmax uses exp2 directly
constexpr float QSCALE = 0.1803368801111244f;

static __device__ inline __bf16 f2bf(float f) {
    unsigned int u = __builtin_bit_cast(unsigned int, f);
    u += 0x7fffu + ((u >> 16) & 1u);
    return __builtin_bit_cast(__bf16, (unsigned short)(u >> 16));
}
#if __has_builtin(__builtin_amdgcn_cvt_pk_bf16_f32)
static __device__ inline bf16x2 pk2(float a, float b) {
    return __builtin_amdgcn_cvt_pk_bf16_f32(a, b);
}
#else
static __device__ inline bf16x2 pk2(float a, float b) {
    bf16x2 r; r[0] = f2bf(a); r[1] = f2bf(b); return r;
}
#endif
#if __has_builtin(__builtin_amdgcn_exp2f)
#define EXP2(x) __builtin_amdgcn_exp2f(x)
#else
#define EXP2(x) exp2f(x)
#endif
static __device__ inline bf16x8 cvt8(floatx4 lo, floatx4 hi) {
    uintx4 w;
    w[0] = __builtin_bit_cast(uint32, pk2(lo[0], lo[1]));
    w[1] = __builtin_bit_cast(uint32, pk2(lo[2], lo[3]));
    w[2] = __builtin_bit_cast(uint32, pk2(hi[0], hi[1]));
    w[3] = __builtin_bit_cast(uint32, pk2(hi[2], hi[3]));
    return __builtin_bit_cast(bf16x8, w);
}

// Blocked fragment layout (A/B-operand ready, b128 loads, zero conflicts):
//   blk[row>>4][k>>5][lane][8], lane = ((k>>3)&3)*16 + (row&15), slot = k&7
// For a 16-aligned row base R and k-step it (32 k per step):
//   frag = *(bf16x8*)&blk[(size_t)R*512 + it*512 + lane*8]   (512 = 64*8)
// Q/K use the same structure per head; V blocked under key-permutation
//   pi(q,j)=16*(j>=4)+4q+(j&3) (see attn epilogues below).

// ---------------------------------------------------------------------------
// Stage 0: fp32 -> bf16 into the blocked fragment layout.  One WAVE per
// 16-row x 32-col frag-block; lane = (d-group quad, row l16) makes the 1KB
// destination exactly lane-linear -> perfectly coalesced 16B/lane writes.
// Reads are 128B row segments.  Same pk2 rounding -> bit-identical inputs.
// (R9/R10 benches were infra failures at container acquisition — third
// identical resubmit; source audited memory-safe.)
// ---------------------------------------------------------------------------
__global__ __launch_bounds__(256)
void cvt_blk(const float* __restrict__ X, const float* __restrict__ Wq,
             const float* __restrict__ Wp,
             __bf16* __restrict__ Xb, __bf16* __restrict__ Wqb,
             __bf16* __restrict__ Wpb)
{
    const int slice = blockIdx.y;
    const float* src;
    __bf16* dst;
    int nwaves;                        // (rows/16) * 16 k-blocks
    if (slice == 0)      { src = X;  dst = Xb;  nwaves = (2*SEQ/16)*16; }
    else if (slice == 1) { src = Wq; dst = Wqb; nwaves = (3*DIM/16)*16; }
    else                 { src = Wp; dst = Wpb; nwaves = (DIM/16)*16; }
    const int wid  = blockIdx.x * 4 + (threadIdx.x >> 6);
    if (wid >= nwaves) return;
    const int lane = threadIdx.x & 63;
    const int rblk = wid >> 4;          // 16-row stripe
    const int kblk = wid & 15;          // 32-col group
    const int row  = rblk*16 + (lane & 15);
    const int d0   = kblk*32 + (lane >> 4)*8;
    const floatx4 lo = *(const floatx4*)(src + (size_t)row*DIM + d0);
    const floatx4 hi = *(const floatx4*)(src + (size_t)row*DIM + d0 + 4);
    *(bf16x8*)(dst + ((size_t)rblk*16 + kblk)*512 + lane*8) = cvt8(lo, hi);
}

// ---------------------------------------------------------------------------
// Stage 1: qkv = x @ w_qkv^T + b_qkv.  UNCHANGED from R8 (no LDS, no
// barriers, blocked-layout frag loads direct from L2).
// ---------------------------------------------------------------------------
__global__ __launch_bounds__(256)
void gemm_qkv(const __bf16* __restrict__ Xb, const __bf16* __restrict__ Wb,
              const float* __restrict__ bias,
              __bf16* __restrict__ Qb, __bf16* __restrict__ Kb, __bf16* __restrict__ Vb)
{
    const int tid  = threadIdx.x;
    const int lane = tid & 63;
    const int wave = tid >> 6;
    const int quad = lane >> 4;
    const int l16  = lane & 15;
    const int waveM = wave >> 1, waveN = wave & 1;
    const int mBase = blockIdx.x * 128;
    const int nBase = blockIdx.y * 128;
    const int which = nBase >> 9;          // 0=q 1=k 2=v (uniform per block)

    floatx4 zero = {0.f, 0.f, 0.f, 0.f};
    floatx4 acc[4][4];
    for (int i = 0; i < 4; i++)
        for (int j = 0; j < 4; j++) acc[i][j] = zero;

    const __bf16* ga = Xb + (size_t)(mBase + waveM*64)*512 + lane*8;
    const __bf16* gb = Wb + (size_t)(nBase + waveN*64)*512 + lane*8;

    for (int it = 0; it < 16; ++it) {
        bf16x8 af[4], bfr[4];
        for (int mi = 0; mi < 4; mi++)
            af[mi]  = *(const bf16x8*)(ga + mi*8192 + it*512);
        for (int ni = 0; ni < 4; ni++)
            bfr[ni] = *(const bf16x8*)(gb + ni*8192 + it*512);
        if (which == 2) {
            for (int mi = 0; mi < 4; mi++)
                for (int ni = 0; ni < 4; ni++)
                    acc[mi][ni] = MFMA16(af[mi], bfr[ni], acc[mi][ni]);
        } else {
            // transposed: rows = W-rows (d), cols = X-rows (s)
            for (int mi = 0; mi < 4; mi++)
                for (int ni = 0; ni < 4; ni++)
                    acc[mi][ni] = MFMA16(bfr[ni], af[mi], acc[mi][ni]);
        }
    }

    if (which == 2) {
        // V epilogue (normal orientation): rows = s, cols = n/d
        for (int ni = 0; ni < 4; ni++) {
            const int n = nBase + waveN*64 + ni*16 + l16;
            const float bv = bias[n];
            const int h = (n >> 6) & 7;
            const int d = n & 63;
            for (int mi = 0; mi < 4; mi++) {
                const int m0 = mBase + waveM*64 + mi*16 + quad*4;
                const int b  = m0 >> 12;
                const int s0 = m0 & 4095;
                const int bh = (b << 3) | h;
                bf16x4 v;
                for (int rr = 0; rr < 4; rr++) v[rr] = f2bf(acc[mi][ni][rr] + bv);
                size_t off = (((((size_t)bh*128 + (s0 >> 5))*4 + (d >> 4))*64)
                              + ((s0 >> 2) & 3)*16 + (d & 15))*8 + ((s0 >> 4) & 1)*4;
                *(bf16x4*)&Vb[off] = v;
            }
        }
    } else {
        // Q/K epilogue (transposed): rows = d (quad*4+r), cols = s (l16)
        __bf16* dst = (which == 0) ? Qb : Kb;
        for (int ni = 0; ni < 4; ni++) {
            const int n0 = nBase + waveN*64 + ni*16 + quad*4;
            const floatx4 b4 = *(const floatx4*)&bias[n0];
            const int dfull = n0 & 511;           // 0..511 within q or k section
            const int h  = dfull >> 6;
            const int d0 = dfull & 63;            // 4-aligned
            const int lgrp = ((d0 >> 3) & 3)*16 + l16;
            const int half = d0 >> 5;
            const int slot = d0 & 7;              // 0 or 4
            for (int mi = 0; mi < 4; mi++) {
                const int m = mBase + waveM*64 + mi*16 + l16;
                const int b = m >> 12, s = m & 4095;
                const int bh = (b << 3) | h;
                bf16x4 v;
                for (int rr = 0; rr < 4; rr++) {
                    float val = acc[mi][ni][rr] + b4[rr];
                    if (which == 0) val *= QSCALE;
                    v[rr] = f2bf(val);
                }
                size_t off = ((((size_t)bh*256 + (s >> 4))*2 + half)*64 + lgrp)*8 + slot;
                *(bf16x4*)&dst[off] = v;
            }
        }
    }
}

// ---------------------------------------------------------------------------
// Stage 2: flash attention.  q-tile halved 64 -> 32 queries per block
// (qf/oacc/Lt halved -> ~112 regs/wave, fits 128) so __launch_bounds__(256,4)
// gives 4 blocks/CU = 4 waves/SIMD (+33% TLP vs the 3-block ceiling the
// 64-q tile's ~164 regs forced).  Grid 2048 = exactly 2 clean residency
// rounds.  K/V cache traffic doubles to 2GB but stays under L2 aggregate BW
// with the head->XCD clustering (2 heads = 2MB < 4MB L2 per XCD).
// Same chunk math / fragment layouts / exp2 / ones-L as the verified core.
// ---------------------------------------------------------------------------
__global__ __launch_bounds__(256, 4)
void attn_kernel(const __bf16* __restrict__ Qb, const __bf16* __restrict__ Kb,
                 const __bf16* __restrict__ Vb, __bf16* __restrict__ Ao)
{
    __shared__ __bf16 Ob[3][32*68];   // bf16 partial O^T, stride 68
    __shared__ float  Lb[4][32];
    const int tid  = threadIdx.x;
    const int lane = tid & 63;
    const int wave = tid >> 6;
    const int quad = lane >> 4;
    const int l16  = lane & 15;
    // XCD-clustering swizzle: id%8 selects XCD; constant per head.
    // id 0..2047; slot 0..255; bh = (id&7) + 8*(slot>=128); qb = slot&127.
    const int id    = blockIdx.x;
    const int slot  = id >> 3;
    const int bh    = (id & 7) + ((slot >> 7) << 3);
    const int qBase = (slot & 127) * 32;

    const __bf16* qg = Qb + (size_t)bh*256*2*512;
    const __bf16* kg = Kb + (size_t)bh*256*2*512;
    const __bf16* vg = Vb + (size_t)bh*128*4*512;

    bf16x8 qf[2][2];
    for (int t = 0; t < 2; t++)
        for (int hb = 0; hb < 2; hb++)
            qf[t][hb] = *(const bf16x8*)(qg
                + ((size_t)((qBase >> 4) + t)*2 + hb)*512 + lane*8);

    floatx4 zero = {0.f, 0.f, 0.f, 0.f};
    floatx4 oacc[2][4];   // [t][od]: O^T tile, row d=od*16+quad*4+r, col q=t*16+l16
    for (int t = 0; t < 2; t++)
        for (int od = 0; od < 4; od++) oacc[t][od] = zero;
    floatx4 Lt[2];        // ones-MFMA: every row of Lt[t] = L[q=t*16+l16]
    Lt[0] = zero; Lt[1] = zero;

    bf16x8 ones;
    for (int j = 0; j < 8; j++) ones[j] = f2bf(1.0f);

    const int key_begin = wave * 1024;
    const __bf16* kptr = kg + (size_t)(key_begin >> 4)*1024 + lane*8;
    const __bf16* vptr = vg + (size_t)(key_begin >> 5)*2048 + lane*8;

    for (int c = 0; c < 32; ++c) {
        bf16x8 kb00 = *(const bf16x8*)(kptr);
        bf16x8 kb01 = *(const bf16x8*)(kptr + 512);
        bf16x8 kb10 = *(const bf16x8*)(kptr + 1024);
        bf16x8 kb11 = *(const bf16x8*)(kptr + 1536);
        bf16x8 vb0  = *(const bf16x8*)(vptr);
        bf16x8 vb1  = *(const bf16x8*)(vptr + 512);
        bf16x8 vb2  = *(const bf16x8*)(vptr + 1024);
        bf16x8 vb3  = *(const bf16x8*)(vptr + 1536);
        kptr += 2048;
        vptr += 2048;

        for (int t = 0; t < 2; t++) {
            floatx4 z0 = zero, z1 = zero;
            z0 = MFMA16(kb00, qf[t][0], z0);
            z0 = MFMA16(kb01, qf[t][1], z0);
            z1 = MFMA16(kb10, qf[t][0], z1);
            z1 = MFMA16(kb11, qf[t][1], z1);
            float e0[4], e1[4];
            for (int r = 0; r < 4; r++) { e0[r] = EXP2(z0[r]); e1[r] = EXP2(z1[r]); }
            uintx4 w;
            w[0] = __builtin_bit_cast(uint32, pk2(e0[0], e0[1]));
            w[1] = __builtin_bit_cast(uint32, pk2(e0[2], e0[3]));
            w[2] = __builtin_bit_cast(uint32, pk2(e1[0], e1[1]));
            w[3] = __builtin_bit_cast(uint32, pk2(e1[2], e1[3]));
            bf16x8 pb = __builtin_bit_cast(bf16x8, w);
            Lt[t] = MFMA16(ones, pb, Lt[t]);
            oacc[t][0] = MFMA16(vb0, pb, oacc[t][0]);
            oacc[t][1] = MFMA16(vb1, pb, oacc[t][1]);
            oacc[t][2] = MFMA16(vb2, pb, oacc[t][2]);
            oacc[t][3] = MFMA16(vb3, pb, oacc[t][3]);
        }
    }

    // L[q] is replicated across rows of Lt[t]; publish per-wave partials
    if (lane < 16)
        for (int t = 0; t < 2; t++) Lb[wave][t*16 + lane] = Lt[t][0];
    __syncthreads();
    float inv[2];
    for (int t = 0; t < 2; t++) {
        const int q = t*16 + l16;
        inv[t] = 1.0f / (Lb[0][q] + Lb[1][q] + Lb[2][q] + Lb[3][q]);
    }
    if (wave != 0) {
        for (int t = 0; t < 2; t++)
            for (int od = 0; od < 4; od++) {
                bf16x4 v;
                for (int r = 0; r < 4; r++) v[r] = f2bf(oacc[t][od][r] * inv[t]);
                *(bf16x4*)&Ob[wave-1][(t*16 + l16)*68 + od*16 + quad*4] = v;
            }
    }
    __syncthreads();
    if (wave == 0) {
        const int b = bh >> 3, h = bh & 7;
        for (int t = 0; t < 2; t++) {
            // global row = b*4096 + qBase + t*16 + l16; row>>4 = b*256+qBase/16+t
            const size_t rtop = (size_t)b*256 + (qBase >> 4) + t;
            for (int od = 0; od < 4; od++) {
                bf16x4 o0 = *(const bf16x4*)&Ob[0][(t*16 + l16)*68 + od*16 + quad*4];
                bf16x4 o1 = *(const bf16x4*)&Ob[1][(t*16 + l16)*68 + od*16 + quad*4];
                bf16x4 o2 = *(const bf16x4*)&Ob[2][(t*16 + l16)*68 + od*16 + quad*4];
                bf16x4 v;
                for (int r = 0; r < 4; r++) {
                    float o = oacc[t][od][r] * inv[t] +
                              (float)o0[r] + (float)o1[r] + (float)o2[r];
                    v[r] = f2bf(o);
                }
                // c = h*64 + od*16 + quad*4 + r  ->  blocked offset:
                const size_t off8 = (rtop*16 + h*2 + (od >> 1))*64
                                    + ((od*2 + (quad >> 1)) & 3)*16 + l16;
                *(bf16x4*)&Ao[off8*8 + (quad & 1)*4] = v;
            }
        }
    }
}

// ---------------------------------------------------------------------------
// Stage 3: out = attn_out @ w_proj^T + b_proj.  UNCHANGED from R8 (no LDS,
// no barriers; A from blocked attn output, B from blocked W_proj).
// ---------------------------------------------------------------------------
__global__ __launch_bounds__(256)
void gemm_proj(const __bf16* __restrict__ Ab, const __bf16* __restrict__ Wb,
               const float* __restrict__ bias, float* __restrict__ Out)
{
    const int tid  = threadIdx.x;
    const int lane = tid & 63;
    const int wave = tid >> 6;
    const int quad = lane >> 4;
    const int l16  = lane & 15;
    const int waveM = wave >> 1, waveN = wave & 1;
    const int mBase = blockIdx.x * 64;
    const int nBase = blockIdx.y * 64;

    floatx4 zero = {0.f, 0.f, 0.f, 0.f};
    floatx4 acc[2][2];
    for (int i = 0; i < 2; i++)
        for (int j = 0; j < 2; j++) acc[i][j] = zero;

    const __bf16* gA = Ab + (size_t)(mBase + waveM*32)*512 + lane*8;
    const __bf16* gB = Wb + (size_t)(nBase + waveN*32)*512 + lane*8;

    for (int it = 0; it < 16; ++it) {
        bf16x8 af[2], bfr[2];
        for (int mi = 0; mi < 2; mi++)
            af[mi]  = *(const bf16x8*)(gA + mi*8192 + it*512);
        for (int ni = 0; ni < 2; ni++)
            bfr[ni] = *(const bf16x8*)(gB + ni*8192 + it*512);
        for (int mi = 0; mi < 2; mi++)
            for (int ni = 0; ni < 2; ni++)
                acc[mi][ni] = MFMA16(af[mi], bfr[ni], acc[mi][ni]);
    }

    for (int ni = 0; ni < 2; ni++) {
        const int n = nBase + waveN*32 + ni*16 + l16;
        const float bv = bias[n];
        for (int mi = 0; mi < 2; mi++) {
            const int m0 = mBase + waveM*32 + mi*16 + quad*4;
            for (int rr = 0; rr < 4; rr++)
                Out[(size_t)(m0 + rr)*DIM + n] = acc[mi][ni][rr] + bv;
        }
    }
}

extern "C" void kernel_launch(void* const* d_in, const int* in_sizes, int n_in,
                              void* d_out, int out_size, void* d_ws, size_t ws_size,
                              hipStream_t stream) {
    const float* x      = (const float*)d_in[0];   // [2,4096,512] fp32
    const float* w_qkv  = (const float*)d_in[1];   // [1536,512] fp32
    const float* b_qkv  = (const float*)d_in[2];   // [1536] fp32
    const float* w_proj = (const float*)d_in[3];   // [512,512] fp32
    const float* b_proj = (const float*)d_in[4];   // [512] fp32
    float* out = (float*)d_out;                    // [2,4096,512] fp32

    __bf16* ws  = (__bf16*)d_ws;
    const size_t PLANE = (size_t)16 * SEQ * HD;    // 4 Mi elements = 8 MB
    __bf16* Qbk = ws;                 // Qblk [16][256][2][64][8] (pre-scaled)
    __bf16* Kbk = ws + PLANE;         // Kblk [16][256][2][64][8]
    __bf16* Vbk = ws + 2*PLANE;       // Vblk [16][128][4][64][8]
    __bf16* Aob = ws + 3*PLANE;       // attn out, blocked [512][16][64][8]
    __bf16* Xb  = ws + 4*PLANE;       // X blocked [512][16][64][8]
    __bf16* Wqb = ws + 5*PLANE;       // W_qkv blocked [96][16][64][8]
    __bf16* Wpb = ws + 5*PLANE + (size_t)3*DIM*DIM;  // W_proj blocked [32][16][64][8]

    cvt_blk<<<dim3(2048, 3), 256, 0, stream>>>(x, w_qkv, w_proj, Xb, Wqb, Wpb);
    gemm_qkv<<<dim3(64, 12), 256, 0, stream>>>(Xb, Wqb, b_qkv, Qbk, Kbk, Vbk);
    attn_kernel<<<dim3(2048), 256, 0, stream>>>(Qbk, Kbk, Vbk, Aob);
    gemm_proj<<<dim3(128, 8), 256, 0, stream>>>(Aob, Wpb, b_proj, out);
}

// Round 12
// 183.901 us; speedup vs baseline: 1.0680x; 1.0680x over previous
//
#include <hip/hip_runtime.h>

typedef __bf16 bf16x8 __attribute__((ext_vector_type(8)));
typedef __bf16 bf16x4 __attribute__((ext_vector_type(4)));
typedef __bf16 bf16x2 __attribute__((ext_vector_type(2)));
typedef float  floatx4 __attribute__((ext_vector_type(4)));
typedef unsigned int uint32;
typedef uint32 uintx4 __attribute__((ext_vector_type(4)));

#define MFMA16(a,b,c) __builtin_amdgcn_mfma_f32_16x16x32_bf16(a,b,c,0,0,0)

constexpr int DIM  = 512;
constexpr int SEQ  = 4096;
constexpr int HD   = 64;
// 0.125 (HEAD_DIM^-0.5) * log2(e), folded into Q so softmax uses exp2 directly
constexpr float QSCALE = 0.1803368801111244f;

static __device__ inline __bf16 f2bf(float f) {
    unsigned int u = __builtin_bit_cast(unsigned int, f);
    u += 0x7fffu + ((u >> 16) & 1u);
    return __builtin_bit_cast(__bf16, (unsigned short)(u >> 16));
}
#if __has_builtin(__builtin_amdgcn_cvt_pk_bf16_f32)
static __device__ inline bf16x2 pk2(float a, float b) {
    return __builtin_amdgcn_cvt_pk_bf16_f32(a, b);
}
#else
static __device__ inline bf16x2 pk2(float a, float b) {
    bf16x2 r; r[0] = f2bf(a); r[1] = f2bf(b); return r;
}
#endif
#if __has_builtin(__builtin_amdgcn_exp2f)
#define EXP2(x) __builtin_amdgcn_exp2f(x)
#else
#define EXP2(x) exp2f(x)
#endif
static __device__ inline bf16x8 cvt8(floatx4 lo, floatx4 hi) {
    uintx4 w;
    w[0] = __builtin_bit_cast(uint32, pk2(lo[0], lo[1]));
    w[1] = __builtin_bit_cast(uint32, pk2(lo[2], lo[3]));
    w[2] = __builtin_bit_cast(uint32, pk2(hi[0], hi[1]));
    w[3] = __builtin_bit_cast(uint32, pk2(hi[2], hi[3]));
    return __builtin_bit_cast(bf16x8, w);
}

// Blocked fragment layout (A/B-operand ready, b128 loads, zero conflicts):
//   blk[row>>4][k>>5][lane][8], lane = ((k>>3)&3)*16 + (row&15), slot = k&7
// For a 16-aligned row base R and k-step it (32 k per step):
//   frag = *(bf16x8*)&blk[(size_t)R*512 + it*512 + lane*8]   (512 = 64*8)
// Q/K use the same structure per head; V blocked under key-permutation
//   pi(q,j)=16*(j>=4)+4q+(j&3) (see attn epilogues below).

// ---------------------------------------------------------------------------
// Stage 0: fp32 -> bf16 into the blocked fragment layout.  R8-verified
// version (R9's "coalesced-write" remap made READS 16-row-scattered and
// measured ~4.6 µs worse — reverted).  Thread i handles 8 consecutive elems
// of a row.  Same pk2 rounding -> bit-identical MFMA inputs.
// ---------------------------------------------------------------------------
__global__ __launch_bounds__(256)
void cvt_blk(const float* __restrict__ X, const float* __restrict__ Wq,
             const float* __restrict__ Wp,
             __bf16* __restrict__ Xb, __bf16* __restrict__ Wqb,
             __bf16* __restrict__ Wpb)
{
    const int slice = blockIdx.y;
    const float* src;
    __bf16* dst;
    int n8;
    if (slice == 0)      { src = X;  dst = Xb;  n8 = (2*SEQ*DIM)/8; }
    else if (slice == 1) { src = Wq; dst = Wqb; n8 = (3*DIM*DIM)/8; }
    else                 { src = Wp; dst = Wpb; n8 = (DIM*DIM)/8; }
    const int i = blockIdx.x * 256 + threadIdx.x;
    if (i >= n8) return;
    const int row = i >> 6;            // /64 (64 x 8-elem slots per 512-row)
    const int d0  = (i & 63) * 8;      // 0..504, 8-aligned
    const floatx4 lo = *(const floatx4*)(src + (size_t)i*8);
    const floatx4 hi = *(const floatx4*)(src + (size_t)i*8 + 4);
    const size_t off8 = ((size_t)(row >> 4)*16 + (d0 >> 5))*64
                        + ((d0 >> 3) & 3)*16 + (row & 15);
    *(bf16x8*)(dst + off8*8) = cvt8(lo, hi);
}

// ---------------------------------------------------------------------------
// Stage 1: qkv = x @ w_qkv^T + b_qkv.  UNCHANGED from R8 (no LDS, no
// barriers, blocked-layout frag loads direct from L2).
// ---------------------------------------------------------------------------
__global__ __launch_bounds__(256)
void gemm_qkv(const __bf16* __restrict__ Xb, const __bf16* __restrict__ Wb,
              const float* __restrict__ bias,
              __bf16* __restrict__ Qb, __bf16* __restrict__ Kb, __bf16* __restrict__ Vb)
{
    const int tid  = threadIdx.x;
    const int lane = tid & 63;
    const int wave = tid >> 6;
    const int quad = lane >> 4;
    const int l16  = lane & 15;
    const int waveM = wave >> 1, waveN = wave & 1;
    const int mBase = blockIdx.x * 128;
    const int nBase = blockIdx.y * 128;
    const int which = nBase >> 9;          // 0=q 1=k 2=v (uniform per block)

    floatx4 zero = {0.f, 0.f, 0.f, 0.f};
    floatx4 acc[4][4];
    for (int i = 0; i < 4; i++)
        for (int j = 0; j < 4; j++) acc[i][j] = zero;

    const __bf16* ga = Xb + (size_t)(mBase + waveM*64)*512 + lane*8;
    const __bf16* gb = Wb + (size_t)(nBase + waveN*64)*512 + lane*8;

    for (int it = 0; it < 16; ++it) {
        bf16x8 af[4], bfr[4];
        for (int mi = 0; mi < 4; mi++)
            af[mi]  = *(const bf16x8*)(ga + mi*8192 + it*512);
        for (int ni = 0; ni < 4; ni++)
            bfr[ni] = *(const bf16x8*)(gb + ni*8192 + it*512);
        if (which == 2) {
            for (int mi = 0; mi < 4; mi++)
                for (int ni = 0; ni < 4; ni++)
                    acc[mi][ni] = MFMA16(af[mi], bfr[ni], acc[mi][ni]);
        } else {
            // transposed: rows = W-rows (d), cols = X-rows (s)
            for (int mi = 0; mi < 4; mi++)
                for (int ni = 0; ni < 4; ni++)
                    acc[mi][ni] = MFMA16(bfr[ni], af[mi], acc[mi][ni]);
        }
    }

    if (which == 2) {
        // V epilogue (normal orientation): rows = s, cols = n/d
        for (int ni = 0; ni < 4; ni++) {
            const int n = nBase + waveN*64 + ni*16 + l16;
            const float bv = bias[n];
            const int h = (n >> 6) & 7;
            const int d = n & 63;
            for (int mi = 0; mi < 4; mi++) {
                const int m0 = mBase + waveM*64 + mi*16 + quad*4;
                const int b  = m0 >> 12;
                const int s0 = m0 & 4095;
                const int bh = (b << 3) | h;
                bf16x4 v;
                for (int rr = 0; rr < 4; rr++) v[rr] = f2bf(acc[mi][ni][rr] + bv);
                size_t off = (((((size_t)bh*128 + (s0 >> 5))*4 + (d >> 4))*64)
                              + ((s0 >> 2) & 3)*16 + (d & 15))*8 + ((s0 >> 4) & 1)*4;
                *(bf16x4*)&Vb[off] = v;
            }
        }
    } else {
        // Q/K epilogue (transposed): rows = d (quad*4+r), cols = s (l16)
        __bf16* dst = (which == 0) ? Qb : Kb;
        for (int ni = 0; ni < 4; ni++) {
            const int n0 = nBase + waveN*64 + ni*16 + quad*4;
            const floatx4 b4 = *(const floatx4*)&bias[n0];
            const int dfull = n0 & 511;           // 0..511 within q or k section
            const int h  = dfull >> 6;
            const int d0 = dfull & 63;            // 4-aligned
            const int lgrp = ((d0 >> 3) & 3)*16 + l16;
            const int half = d0 >> 5;
            const int slot = d0 & 7;              // 0 or 4
            for (int mi = 0; mi < 4; mi++) {
                const int m = mBase + waveM*64 + mi*16 + l16;
                const int b = m >> 12, s = m & 4095;
                const int bh = (b << 3) | h;
                bf16x4 v;
                for (int rr = 0; rr < 4; rr++) {
                    float val = acc[mi][ni][rr] + b4[rr];
                    if (which == 0) val *= QSCALE;
                    v[rr] = f2bf(val);
                }
                size_t off = ((((size_t)bh*256 + (s >> 4))*2 + half)*64 + lgrp)*8 + slot;
                *(bf16x4*)&dst[off] = v;
            }
        }
    }
}

// ---------------------------------------------------------------------------
// Stage 2: flash attention — R8-verified 64-q core (84.2 µs), launch_bounds
// (256,3) [NOT 4: unified VGPR+AGPR file -> ~164 regs/wave; forcing 4
// waves/EU spills (R3: FETCH 530MB).  R11 proved more TLP with smaller
// q-tile also loses: 32-q at 4/CU = 93.4 µs (intensity halved)].
// R12 single change: T5 s_setprio(1) around the MFMA clusters — catalog
// m191 measured +4-7% on attn structures with independent waves; zero
// register cost, no structural change.
// ---------------------------------------------------------------------------
__global__ __launch_bounds__(256, 3)
void attn_kernel(const __bf16* __restrict__ Qb, const __bf16* __restrict__ Kb,
                 const __bf16* __restrict__ Vb, __bf16* __restrict__ Ao)
{
    __shared__ __bf16 Ob[3][64*68];   // bf16 partial O^T, stride 68
    __shared__ float  Lb[4][64];
    const int tid  = threadIdx.x;
    const int lane = tid & 63;
    const int wave = tid >> 6;
    const int quad = lane >> 4;
    const int l16  = lane & 15;
    // XCD-clustering swizzle: id%8 selects XCD (round-robin dispatch); keep
    // it constant per head.  bh = (id&7) + 8*(slot>=64), qb = slot&63.
    const int id    = blockIdx.x;          // 0..1023
    const int slot  = id >> 3;             // 0..127
    const int bh    = (id & 7) + ((slot >> 6) << 3);
    const int qBase = (slot & 63) * 64;

    const __bf16* qg = Qb + (size_t)bh*256*2*512;
    const __bf16* kg = Kb + (size_t)bh*256*2*512;
    const __bf16* vg = Vb + (size_t)bh*128*4*512;

    bf16x8 qf[4][2];
    for (int t = 0; t < 4; t++)
        for (int hb = 0; hb < 2; hb++)
            qf[t][hb] = *(const bf16x8*)(qg
                + ((size_t)((qBase >> 4) + t)*2 + hb)*512 + lane*8);

    floatx4 zero = {0.f, 0.f, 0.f, 0.f};
    floatx4 oacc[4][4];   // [t][od]: O^T tile, row d=od*16+quad*4+r, col q=t*16+l16
    for (int t = 0; t < 4; t++)
        for (int od = 0; od < 4; od++) oacc[t][od] = zero;
    floatx4 Lt[4];        // ones-MFMA: every row of Lt[t] = L[q=t*16+l16]
    for (int t = 0; t < 4; t++) Lt[t] = zero;

    bf16x8 ones;
    for (int j = 0; j < 8; j++) ones[j] = f2bf(1.0f);

    const int key_begin = wave * 1024;
    const __bf16* kptr = kg + (size_t)(key_begin >> 4)*1024 + lane*8;
    const __bf16* vptr = vg + (size_t)(key_begin >> 5)*2048 + lane*8;

    for (int c = 0; c < 32; ++c) {
        bf16x8 kb00 = *(const bf16x8*)(kptr);
        bf16x8 kb01 = *(const bf16x8*)(kptr + 512);
        bf16x8 kb10 = *(const bf16x8*)(kptr + 1024);
        bf16x8 kb11 = *(const bf16x8*)(kptr + 1536);
        bf16x8 vb0  = *(const bf16x8*)(vptr);
        bf16x8 vb1  = *(const bf16x8*)(vptr + 512);
        bf16x8 vb2  = *(const bf16x8*)(vptr + 1024);
        bf16x8 vb3  = *(const bf16x8*)(vptr + 1536);
        kptr += 2048;
        vptr += 2048;

        for (int t = 0; t < 4; t++) {
            floatx4 z0 = zero, z1 = zero;
            __builtin_amdgcn_s_setprio(1);
            z0 = MFMA16(kb00, qf[t][0], z0);
            z0 = MFMA16(kb01, qf[t][1], z0);
            z1 = MFMA16(kb10, qf[t][0], z1);
            z1 = MFMA16(kb11, qf[t][1], z1);
            __builtin_amdgcn_s_setprio(0);
            float e0[4], e1[4];
            for (int r = 0; r < 4; r++) { e0[r] = EXP2(z0[r]); e1[r] = EXP2(z1[r]); }
            uintx4 w;
            w[0] = __builtin_bit_cast(uint32, pk2(e0[0], e0[1]));
            w[1] = __builtin_bit_cast(uint32, pk2(e0[2], e0[3]));
            w[2] = __builtin_bit_cast(uint32, pk2(e1[0], e1[1]));
            w[3] = __builtin_bit_cast(uint32, pk2(e1[2], e1[3]));
            bf16x8 pb = __builtin_bit_cast(bf16x8, w);
            __builtin_amdgcn_s_setprio(1);
            Lt[t] = MFMA16(ones, pb, Lt[t]);
            oacc[t][0] = MFMA16(vb0, pb, oacc[t][0]);
            oacc[t][1] = MFMA16(vb1, pb, oacc[t][1]);
            oacc[t][2] = MFMA16(vb2, pb, oacc[t][2]);
            oacc[t][3] = MFMA16(vb3, pb, oacc[t][3]);
            __builtin_amdgcn_s_setprio(0);
        }
    }

    // L[q] is replicated across rows of Lt[t]; publish per-wave partials
    if (lane < 16)
        for (int t = 0; t < 4; t++) Lb[wave][t*16 + lane] = Lt[t][0];
    __syncthreads();
    float inv[4];
    for (int t = 0; t < 4; t++) {
        const int q = t*16 + l16;
        inv[t] = 1.0f / (Lb[0][q] + Lb[1][q] + Lb[2][q] + Lb[3][q]);
    }
    if (wave != 0) {
        for (int t = 0; t < 4; t++)
            for (int od = 0; od < 4; od++) {
                bf16x4 v;
                for (int r = 0; r < 4; r++) v[r] = f2bf(oacc[t][od][r] * inv[t]);
                *(bf16x4*)&Ob[wave-1][(t*16 + l16)*68 + od*16 + quad*4] = v;
            }
    }
    __syncthreads();
    if (wave == 0) {
        const int b = bh >> 3, h = bh & 7;
        for (int t = 0; t < 4; t++) {
            // global row = b*4096 + qBase + t*16 + l16; row>>4 = b*256+qBase/16+t
            const size_t rtop = (size_t)b*256 + (qBase >> 4) + t;
            for (int od = 0; od < 4; od++) {
                bf16x4 o0 = *(const bf16x4*)&Ob[0][(t*16 + l16)*68 + od*16 + quad*4];
                bf16x4 o1 = *(const bf16x4*)&Ob[1][(t*16 + l16)*68 + od*16 + quad*4];
                bf16x4 o2 = *(const bf16x4*)&Ob[2][(t*16 + l16)*68 + od*16 + quad*4];
                bf16x4 v;
                for (int r = 0; r < 4; r++) {
                    float o = oacc[t][od][r] * inv[t] +
                              (float)o0[r] + (float)o1[r] + (float)o2[r];
                    v[r] = f2bf(o);
                }
                // c = h*64 + od*16 + quad*4 + r  ->  blocked offset:
                const size_t off8 = (rtop*16 + h*2 + (od >> 1))*64
                                    + ((od*2 + (quad >> 1)) & 3)*16 + l16;
                *(bf16x4*)&Ao[off8*8 + (quad & 1)*4] = v;
            }
        }
    }
}

// ---------------------------------------------------------------------------
// Stage 3: out = attn_out @ w_proj^T + b_proj.  UNCHANGED from R8 (no LDS,
// no barriers; A from blocked attn output, B from blocked W_proj).
// ---------------------------------------------------------------------------
__global__ __launch_bounds__(256)
void gemm_proj(const __bf16* __restrict__ Ab, const __bf16* __restrict__ Wb,
               const float* __restrict__ bias, float* __restrict__ Out)
{
    const int tid  = threadIdx.x;
    const int lane = tid & 63;
    const int wave = tid >> 6;
    const int quad = lane >> 4;
    const int l16  = lane & 15;
    const int waveM = wave >> 1, waveN = wave & 1;
    const int mBase = blockIdx.x * 64;
    const int nBase = blockIdx.y * 64;

    floatx4 zero = {0.f, 0.f, 0.f, 0.f};
    floatx4 acc[2][2];
    for (int i = 0; i < 2; i++)
        for (int j = 0; j < 2; j++) acc[i][j] = zero;

    const __bf16* gA = Ab + (size_t)(mBase + waveM*32)*512 + lane*8;
    const __bf16* gB = Wb + (size_t)(nBase + waveN*32)*512 + lane*8;

    for (int it = 0; it < 16; ++it) {
        bf16x8 af[2], bfr[2];
        for (int mi = 0; mi < 2; mi++)
            af[mi]  = *(const bf16x8*)(gA + mi*8192 + it*512);
        for (int ni = 0; ni < 2; ni++)
            bfr[ni] = *(const bf16x8*)(gB + ni*8192 + it*512);
        for (int mi = 0; mi < 2; mi++)
            for (int ni = 0; ni < 2; ni++)
                acc[mi][ni] = MFMA16(af[mi], bfr[ni], acc[mi][ni]);
    }

    for (int ni = 0; ni < 2; ni++) {
        const int n = nBase + waveN*32 + ni*16 + l16;
        const float bv = bias[n];
        for (int mi = 0; mi < 2; mi++) {
            const int m0 = mBase + waveM*32 + mi*16 + quad*4;
            for (int rr = 0; rr < 4; rr++)
                Out[(size_t)(m0 + rr)*DIM + n] = acc[mi][ni][rr] + bv;
        }
    }
}

extern "C" void kernel_launch(void* const* d_in, const int* in_sizes, int n_in,
                              void* d_out, int out_size, void* d_ws, size_t ws_size,
                              hipStream_t stream) {
    const float* x      = (const float*)d_in[0];   // [2,4096,512] fp32
    const float* w_qkv  = (const float*)d_in[1];   // [1536,512] fp32
    const float* b_qkv  = (const float*)d_in[2];   // [1536] fp32
    const float* w_proj = (const float*)d_in[3];   // [512,512] fp32
    const float* b_proj = (const float*)d_in[4];   // [512] fp32
    float* out = (float*)d_out;                    // [2,4096,512] fp32

    __bf16* ws  = (__bf16*)d_ws;
    const size_t PLANE = (size_t)16 * SEQ * HD;    // 4 Mi elements = 8 MB
    __bf16* Qbk = ws;                 // Qblk [16][256][2][64][8] (pre-scaled)
    __bf16* Kbk = ws + PLANE;         // Kblk [16][256][2][64][8]
    __bf16* Vbk = ws + 2*PLANE;       // Vblk [16][128][4][64][8]
    __bf16* Aob = ws + 3*PLANE;       // attn out, blocked [512][16][64][8]
    __bf16* Xb  = ws + 4*PLANE;       // X blocked [512][16][64][8]
    __bf16* Wqb = ws + 5*PLANE;       // W_qkv blocked [96][16][64][8]
    __bf16* Wpb = ws + 5*PLANE + (size_t)3*DIM*DIM;  // W_proj blocked [32][16][64][8]

    cvt_blk<<<dim3(2048, 3), 256, 0, stream>>>(x, w_qkv, w_proj, Xb, Wqb, Wpb);
    gemm_qkv<<<dim3(64, 12), 256, 0, stream>>>(Xb, Wqb, b_qkv, Qbk, Kbk, Vbk);
    attn_kernel<<<dim3(1024), 256, 0, stream>>>(Qbk, Kbk, Vbk, Aob);
    gemm_proj<<<dim3(128, 8), 256, 0, stream>>>(Aob, Wpb, b_proj, out);
}